// Round 2
// 243.440 us; speedup vs baseline: 1.0558x; 1.0558x over previous
//
#include <hip/hip_runtime.h>
#include <hip/hip_bf16.h>

// ---------- types ----------
typedef __attribute__((ext_vector_type(8))) short short8;   // 8 x bf16 (4 VGPRs)
typedef __attribute__((ext_vector_type(4))) float f32x4;    // 16x16 MFMA accumulator

typedef unsigned short u16;

__device__ __forceinline__ u16 f32_to_bf16(float f) {
    unsigned int u = __float_as_uint(f);
    u += 0x7fffu + ((u >> 16) & 1u);   // round-to-nearest-even
    return (u16)(u >> 16);
}

// async global->LDS, 16B per lane; LDS dest = wave-uniform base + lane*16
__device__ __forceinline__ void gload16(const u16* g, u16* lds_base) {
    __builtin_amdgcn_global_load_lds(
        (const __attribute__((address_space(1))) void*)g,
        (__attribute__((address_space(3))) void*)lds_base, 16, 0, 0);
}

// raw barrier + compile-time scheduling fence (rule #18: sched_barrier after
// sync points so hipcc can't hoist/sink LDS reads or MFMA across them)
__device__ __forceinline__ void phase_bar() {
    __builtin_amdgcn_s_barrier();
    __builtin_amdgcn_sched_barrier(0);
}
__device__ __forceinline__ void wait_vm8() {
    asm volatile("s_waitcnt vmcnt(8)" ::: "memory");
    __builtin_amdgcn_sched_barrier(0);
}
__device__ __forceinline__ void wait_vm0() {
    asm volatile("s_waitcnt vmcnt(0)" ::: "memory");
    __builtin_amdgcn_sched_barrier(0);
}

// ---------- fused input cast: x then W, fp32 -> bf16, 4 elems/thread ----------
__global__ void cast_inputs(const float* __restrict__ x, u16* __restrict__ Xb,
                            const float* __restrict__ W, u16* __restrict__ Wb,
                            int nx4, int nw4) {
    int i = blockIdx.x * blockDim.x + threadIdx.x;
    const float* in; u16* out; int idx;
    if (i < nx4) { in = x; out = Xb; idx = i; }
    else { idx = i - nx4; if (idx >= nw4) return; in = W; out = Wb; }
    float4 v = ((const float4*)in)[idx];
    ushort4 o;
    o.x = f32_to_bf16(v.x); o.y = f32_to_bf16(v.y);
    o.z = f32_to_bf16(v.z); o.w = f32_to_bf16(v.w);
    ((ushort4*)out)[idx] = o;
}

// ============================================================================
// 256x256-tile 8-phase GEMM core (HK/m201-style schedule, plain HIP).
// C = A[M,K] * Bt[N,K]^T, both row-major, K contiguous, all dims % 256/128.
// 512 threads = 8 waves (2M x 4N), per-wave output 128x64, acc[8][4] f32x4.
// LDS 128 KiB: double-buffered A[256x64] + B[256x64] bf16 per K-tile.
// XOR chunk swizzle (slot p holds global chunk p^(row&7)) carried over from
// the session's 128^2 core — measured 0 SQ_LDS_BANK_CONFLICT for this exact
// 16x16x32 fragment read pattern.
// Schedule per iteration (2 K-tiles, 8 phases, 2 barriers/phase):
//   P1: rd A-mh0 + B-nh0          | MFMA Q(0,0)
//   P2: rd B-nh1                  | MFMA Q(0,1)
//   P3: rd A-mh1 ; stage B(t+2)   | MFMA Q(1,1)   (bufB free after P2)
//   P4: stage A(t+2)              | MFMA Q(1,0) ; vmcnt(8)  (bufA free after P3)
//   P5..P8: same on buf1 / tile t+1, staging t+3, vmcnt(8) at P8.
// vmcnt(8) = exactly the 8 stage-instructions issued after the guarded tile;
// never drained to 0 in the main loop (T4). Safety: every ds_read is consumed
// by its same-phase MFMA (lgkm waits) before the phase-end barrier, and the
// overwriting stage is issued only after that barrier. vmcnt(8) sits BEFORE
// the phase-end barrier so each wave's own loads for the next buffer have
// landed before any wave proceeds to read it.
// ============================================================================

struct Acc256 { f32x4 acc[8][4]; };

template<int MH>
__device__ __forceinline__ void rd_a(const u16* __restrict__ sA, int wr, int lane,
                                     int lr, short8 (&af)[4][2]) {
#pragma unroll
    for (int a2 = 0; a2 < 4; ++a2) {
        const int row = wr * 128 + MH * 64 + a2 * 16 + lr;
#pragma unroll
        for (int k2 = 0; k2 < 2; ++k2) {
            const int cb = (lane >> 4) + k2 * 4;
            af[a2][k2] = *(const short8*)(sA + row * 64 + ((cb ^ (lr & 7)) * 8));
        }
    }
}

template<int NH>
__device__ __forceinline__ void rd_b(const u16* __restrict__ sB, int wc, int lane,
                                     int lr, short8 (&bf)[2][2]) {
#pragma unroll
    for (int b2 = 0; b2 < 2; ++b2) {
        const int row = wc * 64 + NH * 32 + b2 * 16 + lr;
#pragma unroll
        for (int k2 = 0; k2 < 2; ++k2) {
            const int cb = (lane >> 4) + k2 * 4;
            bf[b2][k2] = *(const short8*)(sB + row * 64 + ((cb ^ (lr & 7)) * 8));
        }
    }
}

template<int MH, int NH>
__device__ __forceinline__ void mm_q(Acc256& fr, const short8 (&af)[4][2],
                                     const short8 (&bf)[2][2]) {
    __builtin_amdgcn_s_setprio(1);
#pragma unroll
    for (int a2 = 0; a2 < 4; ++a2)
#pragma unroll
        for (int b2 = 0; b2 < 2; ++b2)
#pragma unroll
            for (int k2 = 0; k2 < 2; ++k2)
                fr.acc[MH * 4 + a2][NH * 2 + b2] =
                    __builtin_amdgcn_mfma_f32_16x16x32_bf16(
                        af[a2][k2], bf[b2][k2],
                        fr.acc[MH * 4 + a2][NH * 2 + b2], 0, 0, 0);
    __builtin_amdgcn_s_setprio(0);
}

__device__ __forceinline__ void gemm_core_256(
    const u16* __restrict__ A, const u16* __restrict__ Bt,
    int K, int lda, int ldb, int row0, int col0, u16* sm, Acc256& fr)
{
    const int t    = threadIdx.x;
    const int lane = t & 63;
    const int wave = t >> 6;
    const int wr   = wave >> 2;        // 0..1 (M)
    const int wc   = wave & 3;         // 0..3 (N)
    const int lr   = lane & 15;
    const int srow = lane >> 3;
    const int gc   = (lane & 7) ^ srow;

    const u16* const sA0 = sm;
    const u16* const sA1 = sm + 16384;
    const u16* const sB0 = sm + 32768;
    const u16* const sB1 = sm + 49152;

#pragma unroll
    for (int a = 0; a < 8; ++a)
#pragma unroll
        for (int b = 0; b < 4; ++b)
            fr.acc[a][b] = (f32x4){0.f, 0.f, 0.f, 0.f};

    const u16* aB = A  + (long long)(row0 + wave * 8 + srow) * lda + gc * 8;
    const u16* bB = Bt + (long long)(col0 + wave * 8 + srow) * ldb + gc * 8;
    u16* const sAw = sm + wave * 512;            // + buf*16384 + r4*4096
    u16* const sBw = sm + 32768 + wave * 512;

    auto stageA = [&](int kt) {
        u16* d = sAw + (kt & 1) * 16384;
        const u16* g = aB + kt * 64;
#pragma unroll
        for (int r4 = 0; r4 < 4; ++r4)
            gload16(g + (long long)(r4 * 64) * lda, d + r4 * 4096);
    };
    auto stageB = [&](int kt) {
        u16* d = sBw + (kt & 1) * 16384;
        const u16* g = bB + kt * 64;
#pragma unroll
        for (int r4 = 0; r4 < 4; ++r4)
            gload16(g + (long long)(r4 * 64) * ldb, d + r4 * 4096);
    };

    // prologue: tiles 0 (buf0) and 1 (buf1); wait until tile0's 8 loads landed
    stageA(0); stageB(0); stageA(1); stageB(1);
    wait_vm8();
    phase_bar();

    const int NI = K >> 7;             // 2 K-tiles (128 elems of K) per iter
    short8 af[4][2], bfa[2][2], bfb[2][2];
#pragma unroll 1
    for (int i = 0; i < NI; ++i) {
        const bool more = (i + 1 < NI);
        const int t2 = 2 * i + 2;

        // -------- K-tile 2i (buf0) --------
        rd_a<0>(sA0, wr, lane, lr, af);
        rd_b<0>(sB0, wc, lane, lr, bfa);
        phase_bar();
        mm_q<0, 0>(fr, af, bfa);
        phase_bar();

        rd_b<1>(sB0, wc, lane, lr, bfb);
        phase_bar();
        mm_q<0, 1>(fr, af, bfb);
        phase_bar();

        rd_a<1>(sA0, wr, lane, lr, af);
        if (more) stageB(t2);
        phase_bar();
        mm_q<1, 1>(fr, af, bfb);
        phase_bar();

        if (more) stageA(t2);
        phase_bar();
        mm_q<1, 0>(fr, af, bfa);
        if (more) wait_vm8(); else wait_vm0();   // guard tile 2i+1 before P5
        phase_bar();

        // -------- K-tile 2i+1 (buf1) --------
        rd_a<0>(sA1, wr, lane, lr, af);
        rd_b<0>(sB1, wc, lane, lr, bfa);
        phase_bar();
        mm_q<0, 0>(fr, af, bfa);
        phase_bar();

        rd_b<1>(sB1, wc, lane, lr, bfb);
        phase_bar();
        mm_q<0, 1>(fr, af, bfb);
        phase_bar();

        rd_a<1>(sA1, wr, lane, lr, af);
        if (more) stageB(t2 + 1);
        phase_bar();
        mm_q<1, 1>(fr, af, bfb);
        phase_bar();

        if (more) stageA(t2 + 1);
        phase_bar();
        mm_q<1, 0>(fr, af, bfa);
        if (more) wait_vm8();                    // guard tile 2i+2 before next P1
        phase_bar();
    }
}

// C/D layout (16x16): col = lane&15, row = (lane>>4)*4 + reg   [m89/m91-verified]

// ---------- merged QKV projection, 256^2 8-phase ----------
// grid (12, 32): x<8 -> QK path (256x256 tile -> QK[8192,2048]);
// x>=8 -> V path (256x256 tile, stored transposed -> VT[b][d][s]).
// __launch_bounds__(512, 1): LDS (128 of 160 KiB) caps at 1 block/CU anyway;
// give the register allocator the full budget so nothing spills.
__global__ __launch_bounds__(512, 1) void gemm_qkv(
    const u16* __restrict__ Xb, const u16* __restrict__ Wb,
    u16* __restrict__ QK, u16* __restrict__ VT)
{
    __shared__ u16 sm[65536];          // 128 KiB
    const int row0 = blockIdx.y * 256;
    const bool isV = blockIdx.x >= 8;
    const int col0 = (isV ? (blockIdx.x - 8) : blockIdx.x) * 256;
    const u16* Bp  = isV ? (Wb + 2048 * 1024) : Wb;

    Acc256 fr;
    gemm_core_256(Xb, Bp, 1024, 1024, 1024, row0, col0, sm, fr);

    const int lane = threadIdx.x & 63;
    const int wave = threadIdx.x >> 6;
    const int wr = wave >> 2, wc = wave & 3;
    const int cr = (lane >> 4) * 4, cc = lane & 15;

    if (!isV) {
#pragma unroll
        for (int a = 0; a < 8; ++a)
#pragma unroll
            for (int b = 0; b < 4; ++b)
#pragma unroll
                for (int r = 0; r < 4; ++r) {
                    int grow = row0 + wr * 128 + a * 16 + cr + r;
                    int gcol = col0 + wc * 64 + b * 16 + cc;
                    QK[(long long)grow * 2048 + gcol] = f32_to_bf16(fr.acc[a][b][r]);
                }
    } else {
#pragma unroll
        for (int a = 0; a < 8; ++a) {
            int grow = row0 + wr * 128 + a * 16 + cr;   // s (4-aligned)
            int bz = grow >> 11, s = grow & 2047;
#pragma unroll
            for (int b = 0; b < 4; ++b) {
                int d = col0 + wc * 64 + b * 16 + cc;
                ushort4 o;
                o.x = f32_to_bf16(fr.acc[a][b][0]);
                o.y = f32_to_bf16(fr.acc[a][b][1]);
                o.z = f32_to_bf16(fr.acc[a][b][2]);
                o.w = f32_to_bf16(fr.acc[a][b][3]);
                *(ushort4*)(&VT[((long long)(bz * 1024 + d)) * 2048 + s]) = o;
            }
        }
    }
}

// ---------- S GEMM + fused unnormalized softmax, 256^2 8-phase ----------
// E[b] = exp(Q[b]*K[b]^T / 32)  (bf16, no max subtraction: logits ~N(0,1),
// |s|<~6 — exp < ~500, fp32-safe). Row sums -> l[8192] (fp32) via 16-lane
// shuffle pre-reduction + one atomicAdd per row per wave.
__global__ __launch_bounds__(512, 1) void gemm_s_exp(
    const u16* __restrict__ QK, u16* __restrict__ E, float* __restrict__ l)
{
    __shared__ u16 sm[65536];
    const long long boff = (long long)blockIdx.z * 2048 * 2048;
    const u16* Q  = QK + boff;
    const u16* Kp = QK + boff + 1024;
    u16* Eb = E + boff;
    float* lb = l + (long long)blockIdx.z * 2048;
    const int row0 = blockIdx.y * 256;
    const int col0 = blockIdx.x * 256;

    Acc256 fr;
    gemm_core_256(Q, Kp, 1024, 2048, 2048, row0, col0, sm, fr);

    const int lane = threadIdx.x & 63;
    const int wave = threadIdx.x >> 6;
    const int wr = wave >> 2, wc = wave & 3;
    const int cr = (lane >> 4) * 4, cc = lane & 15;

#pragma unroll
    for (int a = 0; a < 8; ++a) {
        float rs[4] = {0.f, 0.f, 0.f, 0.f};
#pragma unroll
        for (int b = 0; b < 4; ++b)
#pragma unroll
            for (int r = 0; r < 4; ++r) {
                float e = __expf(fr.acc[a][b][r] * 0.03125f);
                rs[r] += e;
                int grow = row0 + wr * 128 + a * 16 + cr + r;
                int gcol = col0 + wc * 64 + b * 16 + cc;
                Eb[(long long)grow * 2048 + gcol] = f32_to_bf16(e);
            }
#pragma unroll
        for (int r = 0; r < 4; ++r) {
#pragma unroll
            for (int m = 1; m < 16; m <<= 1) rs[r] += __shfl_xor(rs[r], m, 64);
            if ((lane & 15) == 0)
                atomicAdd(&lb[row0 + wr * 128 + a * 16 + cr + r], rs[r]);
        }
    }
}

// ======== legacy 128^2 core (kept for PV: its 256^2 grid would be only 128
// blocks = half the CUs at 1 block/CU; 128^2 at 512 blocks wins end-to-end) ===

struct Frag128 { f32x4 acc[4][4]; int lane, wm, wn; };

__device__ __forceinline__ void gemm_core_128(
    const u16* __restrict__ A, const u16* __restrict__ Bt, int K, int lda, int ldb,
    int row0, int col0, u16* sA, u16* sB, Frag128& fr)
{
    const int t    = threadIdx.x;
    const int lane = t & 63;
    const int wave = t >> 6;
    fr.lane = lane;
    fr.wm = (wave >> 1) * 64;
    fr.wn = (wave & 1) * 64;
    const int lr = lane & 15;

#pragma unroll
    for (int i = 0; i < 4; ++i)
#pragma unroll
        for (int j = 0; j < 4; ++j)
            fr.acc[i][j] = (f32x4){0.f, 0.f, 0.f, 0.f};

    const int srow = lane >> 3;
    const int gc   = (lane & 7) ^ srow;
    for (int k0 = 0; k0 < K; k0 += 64) {
        __syncthreads();
#pragma unroll
        for (int c = 0; c < 4; ++c) {
            const int rb = c * 32 + wave * 8;
            const int r  = rb + srow;
            gload16(A  + (long long)(row0 + r) * lda + k0 + gc * 8, &sA[rb * 64]);
            gload16(Bt + (long long)(col0 + r) * ldb + k0 + gc * 8, &sB[rb * 64]);
        }
        __syncthreads();

#pragma unroll
        for (int kk = 0; kk < 64; kk += 32) {
            const int cb = (lane >> 4) + (kk >> 3);
            const int sl = (cb ^ (lr & 7)) * 8;
            short8 af[4], bf[4];
#pragma unroll
            for (int i = 0; i < 4; ++i) {
                af[i] = *(const short8*)(&sA[(fr.wm + i * 16 + lr) * 64 + sl]);
                bf[i] = *(const short8*)(&sB[(fr.wn + i * 16 + lr) * 64 + sl]);
            }
#pragma unroll
            for (int i = 0; i < 4; ++i)
#pragma unroll
                for (int j = 0; j < 4; ++j)
                    fr.acc[i][j] = __builtin_amdgcn_mfma_f32_16x16x32_bf16(
                        af[i], bf[j], fr.acc[i][j], 0, 0, 0);
        }
    }
}

// ---------- PV GEMM, transposed + row-scale: Y^T[b] = VT[b] * E[b]^T / l ----
__global__ __launch_bounds__(256) void gemm_pv_ts(
    const u16* __restrict__ E, const u16* __restrict__ VT,
    const float* __restrict__ l, float* __restrict__ Y)
{
    __shared__ u16 sA[128 * 64];
    __shared__ u16 sB[128 * 64];
    const u16* VTb = VT + (long long)blockIdx.z * 1024 * 2048;
    const u16* Eb  = E  + (long long)blockIdx.z * 2048 * 2048;
    const float* lb = l + (long long)blockIdx.z * 2048;
    float* Yb = Y + (long long)blockIdx.z * 2048 * 1024;
    const int row0 = blockIdx.y * 128;   // d
    const int col0 = blockIdx.x * 128;   // q
    Frag128 fr;
    gemm_core_128(VTb, Eb, 2048, 2048, 2048, row0, col0, sA, sB, fr);
    const int cr = (fr.lane >> 4) * 4, cc = fr.lane & 15;
#pragma unroll
    for (int j = 0; j < 4; ++j) {
        int q = col0 + fr.wn + j * 16 + cc;
        float inv = 1.0f / lb[q];
#pragma unroll
        for (int i = 0; i < 4; ++i) {
            int d = row0 + fr.wm + i * 16 + cr;          // 4-aligned
            float4 o = {fr.acc[i][j][0] * inv, fr.acc[i][j][1] * inv,
                        fr.acc[i][j][2] * inv, fr.acc[i][j][3] * inv};
            *(float4*)(&Yb[(long long)q * 1024 + d]) = o;
        }
    }
}

// ---------- launch ----------
extern "C" void kernel_launch(void* const* d_in, const int* in_sizes, int n_in,
                              void* d_out, int out_size, void* d_ws, size_t ws_size,
                              hipStream_t stream) {
    const float* x = (const float*)d_in[0];   // [4,2048,1024]
    const float* W = (const float*)d_in[1];   // [3072,1024]
    float* out = (float*)d_out;               // [4,2048,1024]

    char* ws = (char*)d_ws;
    // layout (bytes): Xb 16.8M | Wb 6.3M | QK 33.6M | VT 16.8M | E 33.6M | l 32K
    u16*   Xb = (u16*)(ws);
    u16*   Wb = (u16*)(ws + 16777216LL);
    u16*   QK = (u16*)(ws + 23068672LL);
    u16*   VT = (u16*)(ws + 56623104LL);
    u16*   E  = (u16*)(ws + 73400320LL);
    float* l  = (float*)(ws + 106954752LL);

    // zero the softmax-denominator accumulator (ws is poisoned 0xAA each call)
    hipMemsetAsync(l, 0, 8192 * sizeof(float), stream);

    cast_inputs<<<11264, 256, 0, stream>>>(x, Xb, W, Wb,
                                           8192 * 1024 / 4, 3072 * 1024 / 4);
    gemm_qkv<<<dim3(12, 32, 1), 512, 0, stream>>>(Xb, Wb, QK, VT);
    gemm_s_exp<<<dim3(8, 8, 4), 512, 0, stream>>>(QK, E, l);
    gemm_pv_ts<<<dim3(16, 8, 4), 256, 0, stream>>>(E, VT, l, out);
}

// Round 3
// 239.953 us; speedup vs baseline: 1.0712x; 1.0145x over previous
//
#include <hip/hip_runtime.h>
#include <hip/hip_bf16.h>

// ---------- types ----------
typedef __attribute__((ext_vector_type(8))) short short8;   // 8 x bf16 (4 VGPRs)
typedef __attribute__((ext_vector_type(4))) float f32x4;    // 16x16 MFMA accumulator

typedef unsigned short u16;

__device__ __forceinline__ u16 f32_to_bf16(float f) {
    unsigned int u = __float_as_uint(f);
    u += 0x7fffu + ((u >> 16) & 1u);   // round-to-nearest-even
    return (u16)(u >> 16);
}

// async global->LDS, 16B per lane; LDS dest = wave-uniform base + lane*16
__device__ __forceinline__ void gload16(const u16* g, u16* lds_base) {
    __builtin_amdgcn_global_load_lds(
        (const __attribute__((address_space(1))) void*)g,
        (__attribute__((address_space(3))) void*)lds_base, 16, 0, 0);
}

// raw barrier + compile-time scheduling fence (rule #18: sched_barrier after
// sync points so hipcc can't hoist/sink LDS reads or MFMA across them)
__device__ __forceinline__ void phase_bar() {
    __builtin_amdgcn_s_barrier();
    __builtin_amdgcn_sched_barrier(0);
}
__device__ __forceinline__ void wait_vm8() {
    asm volatile("s_waitcnt vmcnt(8)" ::: "memory");
    __builtin_amdgcn_sched_barrier(0);
}
__device__ __forceinline__ void wait_vm7() {
    asm volatile("s_waitcnt vmcnt(7)" ::: "memory");
    __builtin_amdgcn_sched_barrier(0);
}
__device__ __forceinline__ void wait_vm0() {
    asm volatile("s_waitcnt vmcnt(0)" ::: "memory");
    __builtin_amdgcn_sched_barrier(0);
}

// ---------- fused input cast + l-zero: x then W fp32->bf16, then l=0 --------
__global__ void cast_inputs(const float* __restrict__ x, u16* __restrict__ Xb,
                            const float* __restrict__ W, u16* __restrict__ Wb,
                            float* __restrict__ l,
                            int nx4, int nw4, int nl) {
    int i = blockIdx.x * blockDim.x + threadIdx.x;
    if (i >= nx4 + nw4) {                 // tail blocks: zero softmax denom
        int idx = i - (nx4 + nw4);
        if (idx < nl) l[idx] = 0.f;
        return;
    }
    const float* in; u16* out; int idx;
    if (i < nx4) { in = x; out = Xb; idx = i; }
    else { idx = i - nx4; in = W; out = Wb; }
    float4 v = ((const float4*)in)[idx];
    ushort4 o;
    o.x = f32_to_bf16(v.x); o.y = f32_to_bf16(v.y);
    o.z = f32_to_bf16(v.z); o.w = f32_to_bf16(v.w);
    ((ushort4*)out)[idx] = o;
}

// ============================================================================
// 8-phase GEMM cores (HK/m201-style schedule, plain HIP).
// C = A[M,K] * Bt[N,K]^T, both row-major, K contiguous.
// 512 threads = 8 waves (2M x 4N). XOR chunk swizzle (slot p holds global
// chunk p^(row&7)) — measured 0 SQ_LDS_BANK_CONFLICT for the 16x16x32
// fragment read pattern.
//
// Two tile shapes:
//  * 256x256 (gemm_core_256): per-wave 128x64, acc[8][4], LDS 128 KiB,
//    vmcnt(8). Used by gemm_s_exp (grid 256 = exactly 1 round).
//  * 256x192 (gemm_core_192): per-wave 128x48, acc[8][3], LDS 112 KiB,
//    vmcnt(7) (= 3 B-stage + 4 A-stage instrs after the guarded tile).
//    Used by gemm_qkv so grid = 16x32 = 512 blocks = EXACTLY 2 full rounds
//    at 1 block/CU — fixes the R2-measured 1.5-round tail (384 blocks,
//    Occupancy 14%, dur identical to the 128^2 version at 74.8 us).
//
// Schedule invariants (both cores): counted vmcnt never drained to 0 in the
// main loop; every ds_read consumed by its same-phase MFMA before the
// phase-end barrier; overwriting stage issued only after that barrier;
// vm-wait sits BEFORE the phase-end barrier guarding the next buffer.
// ============================================================================

struct Acc256 { f32x4 acc[8][4]; };
struct Acc192 { f32x4 acc[8][3]; };

template<int MH>
__device__ __forceinline__ void rd_a(const u16* __restrict__ sA, int wr, int lane,
                                     int lr, short8 (&af)[4][2]) {
#pragma unroll
    for (int a2 = 0; a2 < 4; ++a2) {
        const int row = wr * 128 + MH * 64 + a2 * 16 + lr;
#pragma unroll
        for (int k2 = 0; k2 < 2; ++k2) {
            const int cb = (lane >> 4) + k2 * 4;
            af[a2][k2] = *(const short8*)(sA + row * 64 + ((cb ^ (lr & 7)) * 8));
        }
    }
}

// ---- 256-wide B helpers (s_exp core) ----
template<int NH>
__device__ __forceinline__ void rd_b(const u16* __restrict__ sB, int wc, int lane,
                                     int lr, short8 (&bf)[2][2]) {
#pragma unroll
    for (int b2 = 0; b2 < 2; ++b2) {
        const int row = wc * 64 + NH * 32 + b2 * 16 + lr;
#pragma unroll
        for (int k2 = 0; k2 < 2; ++k2) {
            const int cb = (lane >> 4) + k2 * 4;
            bf[b2][k2] = *(const short8*)(sB + row * 64 + ((cb ^ (lr & 7)) * 8));
        }
    }
}

template<int MH, int NH>
__device__ __forceinline__ void mm_q(Acc256& fr, const short8 (&af)[4][2],
                                     const short8 (&bf)[2][2]) {
    __builtin_amdgcn_s_setprio(1);
#pragma unroll
    for (int a2 = 0; a2 < 4; ++a2)
#pragma unroll
        for (int b2 = 0; b2 < 2; ++b2)
#pragma unroll
            for (int k2 = 0; k2 < 2; ++k2)
                fr.acc[MH * 4 + a2][NH * 2 + b2] =
                    __builtin_amdgcn_mfma_f32_16x16x32_bf16(
                        af[a2][k2], bf[b2][k2],
                        fr.acc[MH * 4 + a2][NH * 2 + b2], 0, 0, 0);
    __builtin_amdgcn_s_setprio(0);
}

// ---- 192-wide B helpers (qkv core): per-wave 48 cols = frags {0,1} + {2} ----
__device__ __forceinline__ void rd_b01(const u16* __restrict__ sB, int wc, int lane,
                                       int lr, short8 (&bf)[2][2]) {
#pragma unroll
    for (int b2 = 0; b2 < 2; ++b2) {
        const int row = wc * 48 + b2 * 16 + lr;
#pragma unroll
        for (int k2 = 0; k2 < 2; ++k2) {
            const int cb = (lane >> 4) + k2 * 4;
            bf[b2][k2] = *(const short8*)(sB + row * 64 + ((cb ^ (lr & 7)) * 8));
        }
    }
}

__device__ __forceinline__ void rd_b2(const u16* __restrict__ sB, int wc, int lane,
                                      int lr, short8 (&bf)[2]) {
    const int row = wc * 48 + 32 + lr;
#pragma unroll
    for (int k2 = 0; k2 < 2; ++k2) {
        const int cb = (lane >> 4) + k2 * 4;
        bf[k2] = *(const short8*)(sB + row * 64 + ((cb ^ (lr & 7)) * 8));
    }
}

template<int MH>
__device__ __forceinline__ void mm_b01(Acc192& fr, const short8 (&af)[4][2],
                                       const short8 (&bf)[2][2]) {
    __builtin_amdgcn_s_setprio(1);
#pragma unroll
    for (int a2 = 0; a2 < 4; ++a2)
#pragma unroll
        for (int b2 = 0; b2 < 2; ++b2)
#pragma unroll
            for (int k2 = 0; k2 < 2; ++k2)
                fr.acc[MH * 4 + a2][b2] =
                    __builtin_amdgcn_mfma_f32_16x16x32_bf16(
                        af[a2][k2], bf[b2][k2],
                        fr.acc[MH * 4 + a2][b2], 0, 0, 0);
    __builtin_amdgcn_s_setprio(0);
}

template<int MH>
__device__ __forceinline__ void mm_b2(Acc192& fr, const short8 (&af)[4][2],
                                      const short8 (&bf)[2]) {
    __builtin_amdgcn_s_setprio(1);
#pragma unroll
    for (int a2 = 0; a2 < 4; ++a2)
#pragma unroll
        for (int k2 = 0; k2 < 2; ++k2)
            fr.acc[MH * 4 + a2][2] =
                __builtin_amdgcn_mfma_f32_16x16x32_bf16(
                    af[a2][k2], bf[k2], fr.acc[MH * 4 + a2][2], 0, 0, 0);
    __builtin_amdgcn_s_setprio(0);
}

// ---------------- 256x256 core (unchanged from R2 — verified) ----------------
__device__ __forceinline__ void gemm_core_256(
    const u16* __restrict__ A, const u16* __restrict__ Bt,
    int K, int lda, int ldb, int row0, int col0, u16* sm, Acc256& fr)
{
    const int t    = threadIdx.x;
    const int lane = t & 63;
    const int wave = t >> 6;
    const int wr   = wave >> 2;
    const int wc   = wave & 3;
    const int lr   = lane & 15;
    const int srow = lane >> 3;
    const int gc   = (lane & 7) ^ srow;

    const u16* const sA0 = sm;
    const u16* const sA1 = sm + 16384;
    const u16* const sB0 = sm + 32768;
    const u16* const sB1 = sm + 49152;

#pragma unroll
    for (int a = 0; a < 8; ++a)
#pragma unroll
        for (int b = 0; b < 4; ++b)
            fr.acc[a][b] = (f32x4){0.f, 0.f, 0.f, 0.f};

    const u16* aB = A  + (long long)(row0 + wave * 8 + srow) * lda + gc * 8;
    const u16* bB = Bt + (long long)(col0 + wave * 8 + srow) * ldb + gc * 8;
    u16* const sAw = sm + wave * 512;
    u16* const sBw = sm + 32768 + wave * 512;

    auto stageA = [&](int kt) {
        u16* d = sAw + (kt & 1) * 16384;
        const u16* g = aB + kt * 64;
#pragma unroll
        for (int r4 = 0; r4 < 4; ++r4)
            gload16(g + (long long)(r4 * 64) * lda, d + r4 * 4096);
    };
    auto stageB = [&](int kt) {
        u16* d = sBw + (kt & 1) * 16384;
        const u16* g = bB + kt * 64;
#pragma unroll
        for (int r4 = 0; r4 < 4; ++r4)
            gload16(g + (long long)(r4 * 64) * ldb, d + r4 * 4096);
    };

    stageA(0); stageB(0); stageA(1); stageB(1);
    wait_vm8();
    phase_bar();

    const int NI = K >> 7;
    short8 af[4][2], bfa[2][2], bfb[2][2];
#pragma unroll 1
    for (int i = 0; i < NI; ++i) {
        const bool more = (i + 1 < NI);
        const int t2 = 2 * i + 2;

        rd_a<0>(sA0, wr, lane, lr, af);
        rd_b<0>(sB0, wc, lane, lr, bfa);
        phase_bar();
        mm_q<0, 0>(fr, af, bfa);
        phase_bar();

        rd_b<1>(sB0, wc, lane, lr, bfb);
        phase_bar();
        mm_q<0, 1>(fr, af, bfb);
        phase_bar();

        rd_a<1>(sA0, wr, lane, lr, af);
        if (more) stageB(t2);
        phase_bar();
        mm_q<1, 1>(fr, af, bfb);
        phase_bar();

        if (more) stageA(t2);
        phase_bar();
        mm_q<1, 0>(fr, af, bfa);
        if (more) wait_vm8(); else wait_vm0();
        phase_bar();

        rd_a<0>(sA1, wr, lane, lr, af);
        rd_b<0>(sB1, wc, lane, lr, bfa);
        phase_bar();
        mm_q<0, 0>(fr, af, bfa);
        phase_bar();

        rd_b<1>(sB1, wc, lane, lr, bfb);
        phase_bar();
        mm_q<0, 1>(fr, af, bfb);
        phase_bar();

        rd_a<1>(sA1, wr, lane, lr, af);
        if (more) stageB(t2 + 1);
        phase_bar();
        mm_q<1, 1>(fr, af, bfb);
        phase_bar();

        if (more) stageA(t2 + 1);
        phase_bar();
        mm_q<1, 0>(fr, af, bfa);
        if (more) wait_vm8();
        phase_bar();
    }
}

// ---------------- 256x192 core (qkv) ----------------
// LDS map (u16 offsets): sA0=0, sA1=16384, sB0=32768, sB1=45056 (B buf =
// 192*64 = 12288). Per-iter phases (per K-tile): 16/8/8/16 MFMA.
__device__ __forceinline__ void gemm_core_192(
    const u16* __restrict__ A, const u16* __restrict__ Bt,
    int K, int lda, int ldb, int row0, int col0, u16* sm, Acc192& fr)
{
    const int t    = threadIdx.x;
    const int lane = t & 63;
    const int wave = t >> 6;
    const int wr   = wave >> 2;
    const int wc   = wave & 3;
    const int lr   = lane & 15;
    const int srow = lane >> 3;
    const int gc   = (lane & 7) ^ srow;

    const u16* const sA0 = sm;
    const u16* const sA1 = sm + 16384;
    const u16* const sB0 = sm + 32768;
    const u16* const sB1 = sm + 45056;

#pragma unroll
    for (int a = 0; a < 8; ++a)
#pragma unroll
        for (int b = 0; b < 3; ++b)
            fr.acc[a][b] = (f32x4){0.f, 0.f, 0.f, 0.f};

    const u16* aB = A  + (long long)(row0 + wave * 8 + srow) * lda + gc * 8;
    const u16* bB = Bt + (long long)(col0 + wave * 8 + srow) * ldb + gc * 8;
    u16* const sAw = sm + wave * 512;
    u16* const sBw = sm + 32768 + wave * 512;

    auto stageA = [&](int kt) {                  // 4 loads/wave
        u16* d = sAw + (kt & 1) * 16384;
        const u16* g = aB + kt * 64;
#pragma unroll
        for (int r4 = 0; r4 < 4; ++r4)
            gload16(g + (long long)(r4 * 64) * lda, d + r4 * 4096);
    };
    auto stageB = [&](int kt) {                  // 3 loads/wave (192 rows)
        u16* d = sBw + (kt & 1) * 12288;
        const u16* g = bB + kt * 64;
#pragma unroll
        for (int r4 = 0; r4 < 3; ++r4)
            gload16(g + (long long)(r4 * 64) * ldb, d + r4 * 4096);
    };

    // prologue: tiles 0,1; 7 loads/tile → guard tile0 with vmcnt(7)
    stageA(0); stageB(0); stageA(1); stageB(1);
    wait_vm7();
    phase_bar();

    const int NI = K >> 7;
    short8 af[4][2], bfa[2][2], bfb[2];
#pragma unroll 1
    for (int i = 0; i < NI; ++i) {
        const bool more = (i + 1 < NI);
        const int t2 = 2 * i + 2;

        // -------- K-tile 2i (buf0) --------
        rd_a<0>(sA0, wr, lane, lr, af);
        rd_b01(sB0, wc, lane, lr, bfa);
        phase_bar();
        mm_b01<0>(fr, af, bfa);
        phase_bar();

        rd_b2(sB0, wc, lane, lr, bfb);
        phase_bar();
        mm_b2<0>(fr, af, bfb);
        phase_bar();

        rd_a<1>(sA0, wr, lane, lr, af);
        if (more) stageB(t2);
        phase_bar();
        mm_b2<1>(fr, af, bfb);
        phase_bar();

        if (more) stageA(t2);
        phase_bar();
        mm_b01<1>(fr, af, bfa);
        if (more) wait_vm7(); else wait_vm0();   // guard tile 2i+1 before P5
        phase_bar();

        // -------- K-tile 2i+1 (buf1) --------
        rd_a<0>(sA1, wr, lane, lr, af);
        rd_b01(sB1, wc, lane, lr, bfa);
        phase_bar();
        mm_b01<0>(fr, af, bfa);
        phase_bar();

        rd_b2(sB1, wc, lane, lr, bfb);
        phase_bar();
        mm_b2<0>(fr, af, bfb);
        phase_bar();

        rd_a<1>(sA1, wr, lane, lr, af);
        if (more) stageB(t2 + 1);
        phase_bar();
        mm_b2<1>(fr, af, bfb);
        phase_bar();

        if (more) stageA(t2 + 1);
        phase_bar();
        mm_b01<1>(fr, af, bfa);
        if (more) wait_vm7();                    // guard tile 2i+2 before next P1
        phase_bar();
    }
}

// C/D layout (16x16): col = lane&15, row = (lane>>4)*4 + reg   [m89/m91-verified]

// ---------- merged QKV projection, 256x192 8-phase ----------
// grid (16, 32) = 512 blocks = exactly 2 full rounds at 1 block/CU.
// B = full Wb[3072,1024]; output column gcol < 2048 -> QK, else -> VT
// (boundary is 16-aligned so each fragment is purely one side; branch is
// wave-uniform). Tiles may straddle the boundary.
__global__ __launch_bounds__(512, 1) void gemm_qkv(
    const u16* __restrict__ Xb, const u16* __restrict__ Wb,
    u16* __restrict__ QK, u16* __restrict__ VT)
{
    __shared__ u16 sm[57344];          // 112 KiB
    const int row0 = blockIdx.y * 256;
    const int col0 = blockIdx.x * 192;

    Acc192 fr;
    gemm_core_192(Xb, Wb, 1024, 1024, 1024, row0, col0, sm, fr);

    const int lane = threadIdx.x & 63;
    const int wave = threadIdx.x >> 6;
    const int wr = wave >> 2, wc = wave & 3;
    const int cr = (lane >> 4) * 4, cc = lane & 15;

#pragma unroll
    for (int a = 0; a < 8; ++a) {
        const int grow = row0 + wr * 128 + a * 16 + cr;   // 4-aligned
#pragma unroll
        for (int b = 0; b < 3; ++b) {
            const int gcol = col0 + wc * 48 + b * 16 + cc;
            if (gcol < 2048) {
#pragma unroll
                for (int r = 0; r < 4; ++r)
                    QK[(long long)(grow + r) * 2048 + gcol] =
                        f32_to_bf16(fr.acc[a][b][r]);
            } else {
                const int bz = grow >> 11, s = grow & 2047;
                const int d = gcol - 2048;
                ushort4 o;
                o.x = f32_to_bf16(fr.acc[a][b][0]);
                o.y = f32_to_bf16(fr.acc[a][b][1]);
                o.z = f32_to_bf16(fr.acc[a][b][2]);
                o.w = f32_to_bf16(fr.acc[a][b][3]);
                *(ushort4*)(&VT[((long long)(bz * 1024 + d)) * 2048 + s]) = o;
            }
        }
    }
}

// ---------- S GEMM + fused unnormalized softmax, 256^2 8-phase ----------
// E[b] = exp(Q[b]*K[b]^T / 32)  (bf16, no max subtraction: logits ~N(0,1),
// |s|<~6 — exp < ~500, fp32-safe). Row sums -> l[8192] (fp32) via 16-lane
// shuffle pre-reduction + one atomicAdd per row per wave.
__global__ __launch_bounds__(512, 1) void gemm_s_exp(
    const u16* __restrict__ QK, u16* __restrict__ E, float* __restrict__ l)
{
    __shared__ u16 sm[65536];
    const long long boff = (long long)blockIdx.z * 2048 * 2048;
    const u16* Q  = QK + boff;
    const u16* Kp = QK + boff + 1024;
    u16* Eb = E + boff;
    float* lb = l + (long long)blockIdx.z * 2048;
    const int row0 = blockIdx.y * 256;
    const int col0 = blockIdx.x * 256;

    Acc256 fr;
    gemm_core_256(Q, Kp, 1024, 2048, 2048, row0, col0, sm, fr);

    const int lane = threadIdx.x & 63;
    const int wave = threadIdx.x >> 6;
    const int wr = wave >> 2, wc = wave & 3;
    const int cr = (lane >> 4) * 4, cc = lane & 15;

#pragma unroll
    for (int a = 0; a < 8; ++a) {
        float rs[4] = {0.f, 0.f, 0.f, 0.f};
#pragma unroll
        for (int b = 0; b < 4; ++b)
#pragma unroll
            for (int r = 0; r < 4; ++r) {
                float e = __expf(fr.acc[a][b][r] * 0.03125f);
                rs[r] += e;
                int grow = row0 + wr * 128 + a * 16 + cr + r;
                int gcol = col0 + wc * 64 + b * 16 + cc;
                Eb[(long long)grow * 2048 + gcol] = f32_to_bf16(e);
            }
#pragma unroll
        for (int r = 0; r < 4; ++r) {
#pragma unroll
            for (int m = 1; m < 16; m <<= 1) rs[r] += __shfl_xor(rs[r], m, 64);
            if ((lane & 15) == 0)
                atomicAdd(&lb[row0 + wr * 128 + a * 16 + cr + r], rs[r]);
        }
    }
}

// ======== legacy 128^2 core (kept for PV: 512 blocks at 32 KB LDS gives
// multi-block/CU implicit overlap; 256^2 grid would be only 128 blocks) ======

struct Frag128 { f32x4 acc[4][4]; int lane, wm, wn; };

__device__ __forceinline__ void gemm_core_128(
    const u16* __restrict__ A, const u16* __restrict__ Bt, int K, int lda, int ldb,
    int row0, int col0, u16* sA, u16* sB, Frag128& fr)
{
    const int t    = threadIdx.x;
    const int lane = t & 63;
    const int wave = t >> 6;
    fr.lane = lane;
    fr.wm = (wave >> 1) * 64;
    fr.wn = (wave & 1) * 64;
    const int lr = lane & 15;

#pragma unroll
    for (int i = 0; i < 4; ++i)
#pragma unroll
        for (int j = 0; j < 4; ++j)
            fr.acc[i][j] = (f32x4){0.f, 0.f, 0.f, 0.f};

    const int srow = lane >> 3;
    const int gc   = (lane & 7) ^ srow;
    for (int k0 = 0; k0 < K; k0 += 64) {
        __syncthreads();
#pragma unroll
        for (int c = 0; c < 4; ++c) {
            const int rb = c * 32 + wave * 8;
            const int r  = rb + srow;
            gload16(A  + (long long)(row0 + r) * lda + k0 + gc * 8, &sA[rb * 64]);
            gload16(Bt + (long long)(col0 + r) * ldb + k0 + gc * 8, &sB[rb * 64]);
        }
        __syncthreads();

#pragma unroll
        for (int kk = 0; kk < 64; kk += 32) {
            const int cb = (lane >> 4) + (kk >> 3);
            const int sl = (cb ^ (lr & 7)) * 8;
            short8 af[4], bf[4];
#pragma unroll
            for (int i = 0; i < 4; ++i) {
                af[i] = *(const short8*)(&sA[(fr.wm + i * 16 + lr) * 64 + sl]);
                bf[i] = *(const short8*)(&sB[(fr.wn + i * 16 + lr) * 64 + sl]);
            }
#pragma unroll
            for (int i = 0; i < 4; ++i)
#pragma unroll
                for (int j = 0; j < 4; ++j)
                    fr.acc[i][j] = __builtin_amdgcn_mfma_f32_16x16x32_bf16(
                        af[i], bf[j], fr.acc[i][j], 0, 0, 0);
        }
    }
}

// ---------- PV GEMM, transposed + row-scale: Y^T[b] = VT[b] * E[b]^T / l ----
__global__ __launch_bounds__(256) void gemm_pv_ts(
    const u16* __restrict__ E, const u16* __restrict__ VT,
    const float* __restrict__ l, float* __restrict__ Y)
{
    __shared__ u16 sA[128 * 64];
    __shared__ u16 sB[128 * 64];
    const u16* VTb = VT + (long long)blockIdx.z * 1024 * 2048;
    const u16* Eb  = E  + (long long)blockIdx.z * 2048 * 2048;
    const float* lb = l + (long long)blockIdx.z * 2048;
    float* Yb = Y + (long long)blockIdx.z * 2048 * 1024;
    const int row0 = blockIdx.y * 128;   // d
    const int col0 = blockIdx.x * 128;   // q
    Frag128 fr;
    gemm_core_128(VTb, Eb, 2048, 2048, 2048, row0, col0, sA, sB, fr);
    const int cr = (fr.lane >> 4) * 4, cc = fr.lane & 15;
#pragma unroll
    for (int j = 0; j < 4; ++j) {
        int q = col0 + fr.wn + j * 16 + cc;
        float inv = 1.0f / lb[q];
#pragma unroll
        for (int i = 0; i < 4; ++i) {
            int d = row0 + fr.wm + i * 16 + cr;          // 4-aligned
            float4 o = {fr.acc[i][j][0] * inv, fr.acc[i][j][1] * inv,
                        fr.acc[i][j][2] * inv, fr.acc[i][j][3] * inv};
            *(float4*)(&Yb[(long long)q * 1024 + d]) = o;
        }
    }
}

// ---------- launch ----------
extern "C" void kernel_launch(void* const* d_in, const int* in_sizes, int n_in,
                              void* d_out, int out_size, void* d_ws, size_t ws_size,
                              hipStream_t stream) {
    const float* x = (const float*)d_in[0];   // [4,2048,1024]
    const float* W = (const float*)d_in[1];   // [3072,1024]
    float* out = (float*)d_out;               // [4,2048,1024]

    char* ws = (char*)d_ws;
    // layout (bytes): Xb 16.8M | Wb 6.3M | QK 33.6M | VT 16.8M | E 33.6M | l 32K
    u16*   Xb = (u16*)(ws);
    u16*   Wb = (u16*)(ws + 16777216LL);
    u16*   QK = (u16*)(ws + 23068672LL);
    u16*   VT = (u16*)(ws + 56623104LL);
    u16*   E  = (u16*)(ws + 73400320LL);
    float* l  = (float*)(ws + 106954752LL);

    // cast + l-zero fused (l zeroing replaces the old hipMemsetAsync launch)
    const int nx4 = 8192 * 1024 / 4, nw4 = 3072 * 1024 / 4;
    cast_inputs<<<11296, 256, 0, stream>>>(x, Xb, W, Wb, l, nx4, nw4, 8192);
    gemm_qkv<<<dim3(16, 32, 1), 512, 0, stream>>>(Xb, Wb, QK, VT);
    gemm_s_exp<<<dim3(8, 8, 4), 512, 0, stream>>>(QK, E, l);
    gemm_pv_ts<<<dim3(16, 8, 4), 256, 0, stream>>>(E, VT, l, out);
}